// Round 6
// baseline (33.347 us; speedup 1.0000x reference)
//
#include <hip/hip_runtime.h>
#include <hip/hip_bf16.h>

#define BATCH 64
#define NADJ  512
#define F     128
#define CROP0 128
#define CROP1 384
#define CN    256
#define BN_EPS 1e-5f

typedef __attribute__((ext_vector_type(8))) short short8;
typedef __attribute__((ext_vector_type(4))) float f32x4;

__device__ __forceinline__ ushort f2bf(float x) {
  __hip_bfloat16 h = __float2bfloat16(x);  // RNE
  return *reinterpret_cast<ushort*>(&h);
}

// XCD-aligned swizzle: all 8 tiles of batch b land on XCD (b&7) so St[b]
// stays in one XCD's private L2 across K1 (write) and K2 (read).
// blockIdx.x = x + 8*y, x in [0,8), y in [0,64):  b = (y>>3)*8 + x, tile = y&7
__device__ __forceinline__ void swz(int W, int& b, int& t0) {
  const int x = W & 7, y = W >> 3;
  b  = ((y >> 3) << 3) | x;
  t0 = (y & 7) * 32;
}

// ---------------------------------------------------------------------------
// K1: St[b][f][m] = bf16( (input_crop @ W)^T ), m-tile 32 per block.
// W^T staged in LDS per block: coalesced/full-line global reads,
// conflict-free LDS writes (lane <-> i mapping, 128B-contiguous ushorts).
// ---------------------------------------------------------------------------
__global__ __launch_bounds__(256) void support_k(
    const float* __restrict__ input, const float* __restrict__ W,
    ushort* __restrict__ St) {
  int b, m0;
  swz(blockIdx.x, b, m0);
  __shared__ ushort wt[128][136];  // W^T [f][i]
  __shared__ ushort ain[32][136];  // input tile [m][i]
  const int tid = threadIdx.x;

  // stage W^T: thread covers i = (tid&63)+{0,64}, f = (tid>>6)*32 .. +32
  {
    const int i0 = tid & 63;
    const int fq = (tid >> 6) * 32;
#pragma unroll
    for (int ih = 0; ih < 2; ++ih) {
      const int i = i0 + ih * 64;
      const float* wr = &W[(size_t)i * F + fq];
      float4 v[8];
#pragma unroll
      for (int q = 0; q < 8; ++q)
        v[q] = reinterpret_cast<const float4*>(wr)[q];
#pragma unroll
      for (int q = 0; q < 8; ++q) {
        wt[fq + q * 4 + 0][i] = f2bf(v[q].x);
        wt[fq + q * 4 + 1][i] = f2bf(v[q].y);
        wt[fq + q * 4 + 2][i] = f2bf(v[q].z);
        wt[fq + q * 4 + 3][i] = f2bf(v[q].w);
      }
    }
  }
  // stage input tile 32x128 fp32 -> bf16, coalesced
  const float* inb = input + ((size_t)b * NADJ + CROP0 + m0) * F;
  for (int idx = tid; idx < 32 * 32; idx += 256) {
    const int ml = idx >> 5, c4 = (idx & 31) * 4;
    const float4 v = *reinterpret_cast<const float4*>(&inb[(size_t)ml * F + c4]);
    *reinterpret_cast<ushort4*>(&ain[ml][c4]) =
        make_ushort4(f2bf(v.x), f2bf(v.y), f2bf(v.z), f2bf(v.w));
  }
  __syncthreads();

  const int l = tid & 63, w = tid >> 6;
  const int lr = l & 15, lg = l >> 4;
  const int msub = (w & 1) * 16;
  const int f0   = (w >> 1) * 64;
  f32x4 acc[4] = {};

#pragma unroll
  for (int ks = 0; ks < 4; ++ks) {
    const int k0 = ks * 32 + lg * 8;
    const short8 av = *reinterpret_cast<const short8*>(&ain[msub + lr][k0]);
#pragma unroll
    for (int fi = 0; fi < 4; ++fi) {
      const short8 bv =
          *reinterpret_cast<const short8*>(&wt[f0 + fi * 16 + lr][k0]);
      acc[fi] =
          __builtin_amdgcn_mfma_f32_16x16x32_bf16(av, bv, acc[fi], 0, 0, 0);
    }
  }
  // D: col(f)=lane&15, row(m)=4*(lane>>4)+reg
#pragma unroll
  for (int fi = 0; fi < 4; ++fi) {
    const int f = f0 + fi * 16 + lr;
    *reinterpret_cast<ushort4*>(
        &St[((size_t)b * F + f) * CN + m0 + msub + lg * 4]) =
        make_ushort4(f2bf(acc[fi][0]), f2bf(acc[fi][1]), f2bf(acc[fi][2]),
                     f2bf(acc[fi][3]));
  }
}

// ---------------------------------------------------------------------------
// K2: out_crop[b][n][f] = adj_crop[b][n][:] @ S[b][:][f], n-tile 32 per block.
// adj tile staged in LDS; St B-frags from the same XCD's L2 (swizzle-matched).
// ---------------------------------------------------------------------------
__global__ __launch_bounds__(256) void aggregate_k(
    const float* __restrict__ adj, const ushort* __restrict__ St,
    float* __restrict__ out) {
  int b, n0;
  swz(blockIdx.x, b, n0);
  __shared__ ushort adt[32][264];  // 528B row stride
  const int tid = threadIdx.x;
  const float* adjb = adj + ((size_t)b * NADJ + CROP0 + n0) * NADJ + CROP0;

  for (int idx = tid; idx < 32 * 64; idx += 256) {
    const int nl = idx >> 6, c4 = (idx & 63) * 4;
    const float4 v =
        *reinterpret_cast<const float4*>(&adjb[(size_t)nl * NADJ + c4]);
    *reinterpret_cast<ushort4*>(&adt[nl][c4]) =
        make_ushort4(f2bf(v.x), f2bf(v.y), f2bf(v.z), f2bf(v.w));
  }
  __syncthreads();

  const int l = tid & 63, w = tid >> 6;
  const int lr = l & 15, lg = l >> 4;
  const int nsub = (w & 1) * 16;
  const int f0   = (w >> 1) * 64;
  const ushort* Stb = St + (size_t)b * F * CN;
  f32x4 acc[4] = {};

#pragma unroll 4
  for (int ks = 0; ks < 8; ++ks) {
    const int k0 = ks * 32 + lg * 8;
    const short8 av = *reinterpret_cast<const short8*>(&adt[nsub + lr][k0]);
#pragma unroll
    for (int fi = 0; fi < 4; ++fi) {
      const short8 bv = *reinterpret_cast<const short8*>(
          &Stb[(size_t)(f0 + fi * 16 + lr) * CN + k0]);
      acc[fi] =
          __builtin_amdgcn_mfma_f32_16x16x32_bf16(av, bv, acc[fi], 0, 0, 0);
    }
  }
#pragma unroll
  for (int fi = 0; fi < 4; ++fi) {
    const int f = f0 + fi * 16 + lr;
    const int n = n0 + nsub + lg * 4;
#pragma unroll
    for (int r = 0; r < 4; ++r)
      out[((size_t)b * NADJ + CROP0 + n + r) * F + f] = acc[fi][r];
  }
}

// ---------------------------------------------------------------------------
// K3: fused BN stats + normalize + beta-fill (register-resident x[16]).
// ---------------------------------------------------------------------------
__global__ __launch_bounds__(256) void bn_fused(
    float* __restrict__ out, const float* __restrict__ gamma,
    const float* __restrict__ beta) {
  __shared__ float s_l[256], s2_l[256], m_l[64], r_l[64];
  const int tid = threadIdx.x;
  const int jl = tid & 63, bg = tid >> 6;
  const int j  = blockIdx.x * 64 + jl;  // 0..32767 = nl*128+f
  const int nl = j >> 7, f = j & 127;
  const int nf = (CROP0 + nl) * F + f;
  float* p = out + (size_t)nf + (size_t)bg * 16 * NADJ * F;

  float x[16];
  float s = 0.f, s2 = 0.f;
#pragma unroll
  for (int bb = 0; bb < 16; ++bb) {
    x[bb] = p[(size_t)bb * NADJ * F];
    s += x[bb];
    s2 += x[bb] * x[bb];
  }
  s_l[tid]  = s;
  s2_l[tid] = s2;
  __syncthreads();
  if (tid < 64) {
    s  = s_l[jl] + s_l[64 + jl] + s_l[128 + jl] + s_l[192 + jl];
    s2 = s2_l[jl] + s2_l[64 + jl] + s2_l[128 + jl] + s2_l[192 + jl];
    const float mean = s * (1.f / BATCH);
    const float var  = s2 * (1.f / BATCH) - mean * mean;
    m_l[jl] = mean;
    r_l[jl] = rsqrtf(var + BN_EPS);
  }
  __syncthreads();
  const float mean = m_l[jl];
  const float a    = r_l[jl] * gamma[nf];
  const float c    = beta[nf] - mean * a;
#pragma unroll
  for (int bb = 0; bb < 16; ++bb)
    p[(size_t)bb * NADJ * F] = x[bb] * a + c;

  // beta-fill the non-crop rows
  const int gid0 = blockIdx.x * 256 + tid;
#pragma unroll
  for (int q = 0; q < 4; ++q) {
    const int gid = gid0 + q * 131072;
    const int c4  = (gid & 31) * 4;
    const int rr  = (gid >> 5) & 255;
    const int bb  = gid >> 13;
    const int n   = rr < 128 ? rr : rr + 256;
    const float4 bv =
        *reinterpret_cast<const float4*>(&beta[(size_t)n * F + c4]);
    *reinterpret_cast<float4*>(&out[((size_t)bb * NADJ + n) * F + c4]) = bv;
  }
}

extern "C" void kernel_launch(void* const* d_in, const int* in_sizes, int n_in,
                              void* d_out, int out_size, void* d_ws,
                              size_t ws_size, hipStream_t stream) {
  const float* input = (const float*)d_in[0];
  const float* adj   = (const float*)d_in[1];
  const float* W     = (const float*)d_in[2];
  const float* gamma = (const float*)d_in[3];
  const float* beta  = (const float*)d_in[4];
  float* out = (float*)d_out;

  ushort* St = (ushort*)d_ws;  // 64*128*256 bf16 = 4 MB

  support_k<<<512, 256, 0, stream>>>(input, W, St);
  aggregate_k<<<512, 256, 0, stream>>>(adj, St, out);
  bn_fused<<<512, 256, 0, stream>>>(out, gamma, beta);
}